// Round 1
// 259.985 us; speedup vs baseline: 1.1105x; 1.1105x over previous
//
#include <hip/hip_runtime.h>

// DCGN forward, algebraically collapsed.
//
// Reference structure: propagate's einsum('xyz,abc->xbc') factorizes as
//   g[x,b,c] = (sum_{y,z} adj[x]) * (sum_a h[a,b,c])
// and get_adjacent's diagonal is dinv*d*dinv = 1 (+- ~2.4e-7 fp32 rounding),
// so sum_{y,z} adj[x] = S (360 layer 1, 120 layer 2) up to ~1e-7 relative.
// Hardcoding those scalars makes layer-1 output identical across batch;
// layer 2 + classifier then run once and broadcast x64.
//
// R4 analysis: timed region = 3x 540MB harness ws-poison fills (~246 us at
// 86% HBM peak, not controllable) + ~43 us of our kernels. This revision
// attacks the controllable part: the old k_head ran 784-deep serial dot
// products on 40 blocks (latency-bound, ~8-12 us). Now k_gemm's epilogue
// folds h2c@W2 into 13 partial out2 buffers po[by][120][28] via the same
// readlane-broadcast idiom as its main loop (h2c never materialized), and
// k_head collapses to a 13-way fold + tiny MLP + broadcast (~2 us).
//
// Pipeline (all on `stream`), atomic-free:
//   k_hsum  : x (141.6 MB, the only HBM-heavy pass) ->
//             part[bg][s][f] = sum_{b in group bg} sum_p x[b,3s+p,f]*nc1w[p,f]
//   k_gemm  : hv = sum_bg part[bg] folded into the load phase;
//             h1[s,c] = gelu(360*(hsum@W1)[s,c] + b1[c]) fused with
//             node-conv-2 (h2 rows held in wave-0 registers) fused with
//             partial h2@W2 -> po[by][s2][k]  (h1, h2c never materialized).
//   k_head  : out2[s2,k] = gelu(7680 * sum_by po[by][s2][k] + b2[k]);
//             rows of 84 -> gelu(@cls_w1+b1) -> @cls_w2+b2; broadcast x64.

#define N_   1080
#define F_   512
#define S1_  360
#define H1_  784
#define S2_  120
#define H2_  28
#define NBG  8               // batch groups (64/8)
#define NPO  13              // partial out2 buffers (one per blockIdx.y)
#define PSTRIDE (S1_ * F_)   // floats per partial buffer (184320)

__device__ __forceinline__ float gelu_f(float v) {
  // erf-based gelu (approximate=False)
  return 0.5f * v * (1.0f + erff(v * 0.70710678118654752f));
}

// ---------------------------------------------------------------------------
// Kernel A: part[bg][s][f] = sum_{i<8} sum_p x[8bg+i, 3s+p, f] * nc1w[p, f]
// grid (360, 8), block 128. Thread t owns float4 chunk t of the 512-float row
// (fully coalesced 16B/lane). Register accumulation over 8 batches, one
// float4 store per thread. 5760 waves, no atomics. ~23 us = HBM floor for
// reading x once.
// ---------------------------------------------------------------------------
__global__ __launch_bounds__(128) void k_hsum(
    const float* __restrict__ x, const float* __restrict__ nc1w,
    float* __restrict__ part) {
  const int s = blockIdx.x, bg = blockIdx.y, t = threadIdx.x;
  const float4* __restrict__ x4 = (const float4*)x;
  const float4 w0 = ((const float4*)nc1w)[t];
  const float4 w1 = ((const float4*)nc1w)[128 + t];
  const float4 w2 = ((const float4*)nc1w)[256 + t];
  float ax = 0.f, ay = 0.f, az = 0.f, aw = 0.f;
  // float4 index of x[b0, 3s, 4t]
  size_t base = ((size_t)bg * 8 * N_ + 3 * (size_t)s) * 128 + t;
  #pragma unroll
  for (int i = 0; i < 8; ++i) {
    float4 c0 = x4[base];
    float4 c1 = x4[base + 128];
    float4 c2 = x4[base + 256];
    ax += w0.x * c0.x + w1.x * c1.x + w2.x * c2.x;
    ay += w0.y * c0.y + w1.y * c1.y + w2.y * c2.y;
    az += w0.z * c0.z + w1.z * c1.z + w2.z * c2.z;
    aw += w0.w * c0.w + w1.w * c1.w + w2.w * c2.w;
    base += (size_t)N_ * 128;  // next batch
  }
  float4 r = make_float4(ax, ay, az, aw);
  ((float4*)part)[(size_t)bg * (PSTRIDE / 4) + s * 128 + t] = r;
}

// ---------------------------------------------------------------------------
// Kernel B: for 6 consecutive s-rows (= 2 windows of layer 2):
//   hsum_i[f] = sum_bg part[bg][s0+i][f]           (8-way fold, L2-resident)
//   acc_i = sum_f hsum_i[f] * W1[f, c]             (K=512 fp32 dot)
//   h1_i  = gelu(360*acc_i + b1[c])
//   h2_q[c] = sum_p nc2_w[p,c] * h1_{3q+p}         (q = 0,1; wave-0 regs)
//   po[by][s2+q][k] = sum_{c in this block's 64-col slice} h2_q[c]*W2[c,k]
// Block = 256 threads (4 waves). Wave w reduces the f-slice [128w, 128w+128)
// via per-lane coalesced loads broadcast with v_readlane (VALU pipe);
// cross-wave reduction through 6 KB LDS; wave 0 runs the epilogue, including
// the new 64-step readlane reduction into the partial out2 buffer.
// No early returns before the barrier; c-dependent loads use a clamped
// index, stores are guarded. grid (60, 13), block 256 -> 3120 waves.
// ---------------------------------------------------------------------------
__global__ __launch_bounds__(256) void k_gemm(
    const float* __restrict__ part, const float* __restrict__ W1,
    const float* __restrict__ b1, const float* __restrict__ nc2w,
    const float* __restrict__ W2, float* __restrict__ po) {
  const int t = threadIdx.x;
  const int lane = t & 63, w = t >> 6;
  const int c = blockIdx.y * 64 + lane;
  const int cw = (c < H1_) ? c : (H1_ - 1);  // clamped for safe loads
  const int s0 = blockIdx.x * 6;
  float acc[6] = {0.f, 0.f, 0.f, 0.f, 0.f, 0.f};
  __shared__ float red[4][6][64];

  #pragma unroll
  for (int fi = 0; fi < 2; ++fi) {
    const int f0 = w * 128 + fi * 64;
    float hv[6];
    #pragma unroll
    for (int i = 0; i < 6; ++i) {
      const int off = (s0 + i) * F_ + f0 + lane;
      float a = 0.f;
      #pragma unroll
      for (int bg = 0; bg < NBG; ++bg) a += part[(size_t)bg * PSTRIDE + off];
      hv[i] = a;
    }
    #pragma unroll 8
    for (int j = 0; j < 64; ++j) {
      float wval = W1[(size_t)(f0 + j) * H1_ + cw];
      #pragma unroll
      for (int i = 0; i < 6; ++i) {
        float hs = __int_as_float(
            __builtin_amdgcn_readlane(__float_as_int(hv[i]), j));
        acc[i] += hs * wval;
      }
    }
  }
  #pragma unroll
  for (int i = 0; i < 6; ++i) red[w][i][lane] = acc[i];
  __syncthreads();

  if (w == 0) {
    // h2 values for this block's 64-column slice; lanes with c >= 784
    // contribute exact 0 so the readlane reduction needs no guard.
    float h2a = 0.f, h2b = 0.f;
    if (c < H1_) {
      const float bb = b1[c];
      float hrow[6];
      #pragma unroll
      for (int i = 0; i < 6; ++i) {
        float a = red[0][i][lane] + red[1][i][lane] +
                  red[2][i][lane] + red[3][i][lane];
        hrow[i] = gelu_f(360.0f * a + bb);
      }
      const float w2a = nc2w[c], w2b = nc2w[H1_ + c], w2c = nc2w[2 * H1_ + c];
      h2a = w2a * hrow[0] + w2b * hrow[1] + w2c * hrow[2];
      h2b = w2a * hrow[3] + w2b * hrow[4] + w2c * hrow[5];
    }
    // partial out2: po[by][s2][k] = sum_{j<64} h2[j] * W2[64*by + j, k]
    const int kk = (lane < H2_) ? lane : 0;
    float p0 = 0.f, p1 = 0.f;
    #pragma unroll 8
    for (int j = 0; j < 64; ++j) {
      int cj = blockIdx.y * 64 + j;
      cj = (cj < H1_) ? cj : (H1_ - 1);          // clamped; h2 is 0 there
      const float wv = W2[(size_t)cj * H2_ + kk];
      p0 += __int_as_float(
                __builtin_amdgcn_readlane(__float_as_int(h2a), j)) * wv;
      p1 += __int_as_float(
                __builtin_amdgcn_readlane(__float_as_int(h2b), j)) * wv;
    }
    if (lane < H2_) {
      const int s2 = blockIdx.x * 2;
      po[((size_t)blockIdx.y * S2_ + s2) * H2_ + kk]       = p0;
      po[((size_t)blockIdx.y * S2_ + (s2 + 1)) * H2_ + kk] = p1;
    }
  }
}

// ---------------------------------------------------------------------------
// Kernel C (head): one block per classifier row j (40 rows, common across
// batch). out2[s2,k] = gelu(7680 * sum_by po[by][s2][k] + b2[k])  (13-way
// fold of L2-resident partials -- the 784-deep dot is gone), then the
// 84->32 gelu layer, the 32->10 layer, and broadcast-writes the 10 outputs
// to all 64 batches. grid (40), block 256. Launch-bound, ~2 us.
// ---------------------------------------------------------------------------
__global__ __launch_bounds__(256) void k_head(
    const float* __restrict__ po, const float* __restrict__ b2,
    const float* __restrict__ cw1, const float* __restrict__ cb1,
    const float* __restrict__ cw2, const float* __restrict__ cb2,
    float* __restrict__ out) {
  const int j = blockIdx.x, t = threadIdx.x;
  __shared__ float row84[84];
  __shared__ float mid[32];
  __shared__ float ovec[10];

  if (t < 84) {
    const int p = t / H2_, k = t - p * H2_;      // col = p*28 + k
    const int s2 = 3 * j + p;
    float sum = 0.f;
    #pragma unroll
    for (int by = 0; by < NPO; ++by)
      sum += po[((size_t)by * S2_ + s2) * H2_ + k];
    // scale = A2 * B = 120 * 64 (adj-2 row-sum times batch-sum of h2)
    row84[t] = gelu_f(7680.0f * sum + b2[k]);
  }
  __syncthreads();
  if (t < 32) {
    float acc = cb1[t];
    #pragma unroll 4
    for (int q = 0; q < 84; ++q) acc += row84[q] * cw1[q * 32 + t];
    mid[t] = gelu_f(acc);
  }
  __syncthreads();
  if (t < 10) {
    float acc = cb2[t];
    #pragma unroll
    for (int m = 0; m < 32; ++m) acc += mid[m] * cw2[m * 10 + t];
    ovec[t] = acc;
  }
  __syncthreads();
  // broadcast to all 64 batches: out[(x*40 + j)*10 + k]
  for (int i = t; i < 640; i += 256) {
    const int xx = i / 10, kk = i % 10;
    out[((size_t)xx * 40 + j) * 10 + kk] = ovec[kk];
  }
}

extern "C" void kernel_launch(void* const* d_in, const int* in_sizes, int n_in,
                              void* d_out, int out_size, void* d_ws, size_t ws_size,
                              hipStream_t stream) {
  const float* x    = (const float*)d_in[0];   // [64,1080,512]
  const float* nc1w = (const float*)d_in[1];   // [3,512]
  // d_in[2] gap1_w, d_in[3] gap1_b: only feed the adjacency diagonal (== 1)
  const float* W1   = (const float*)d_in[4];   // [512,784]
  const float* b1   = (const float*)d_in[5];   // [784]
  const float* nc2w = (const float*)d_in[6];   // [3,784]
  // d_in[7] gap2_w, d_in[8] gap2_b: unused (same reason)
  const float* W2   = (const float*)d_in[9];   // [784,28]
  const float* b2   = (const float*)d_in[10];  // [28]
  const float* cw1  = (const float*)d_in[11];  // [84,32]
  const float* cb1  = (const float*)d_in[12];  // [32]
  const float* cw2  = (const float*)d_in[13];  // [32,10]
  const float* cb2  = (const float*)d_in[14];  // [10]
  float* outp = (float*)d_out;

  float* ws   = (float*)d_ws;
  float* part = ws;                        // 8 * 360*512 = 1474560 floats
  float* po   = ws + NBG * PSTRIDE;        // 13*120*28   =   43680 floats

  k_hsum<<<dim3(S1_, 8), 128, 0, stream>>>(x, nc1w, part);
  k_gemm<<<dim3(60, 13), 256, 0, stream>>>(part, W1, b1, nc2w, W2, po);
  k_head<<<dim3(40), 256, 0, stream>>>(po, b2, cw1, cb1, cw2, cb2, outp);
}